// Round 1
// baseline (111.908 us; speedup 1.0000x reference)
//
#include <hip/hip_runtime.h>

// Causal linear attention (elu+1 feature map), chunked-scan formulation.
// Shapes fixed by the reference: N=2, L=2048, H=8, D=64, M=64, fp32.

namespace {
constexpr int N_ = 2, L_ = 2048, H_ = 8, D_ = 64, M_ = 64;
constexpr int C  = 64;            // chunk length
constexpr int G  = L_ / C;        // 32 chunks per sequence
constexpr int NH = N_ * H_;       // 16 independent (n,h) sequences
constexpr int LDH = H_ * D_;      // stride (floats) between consecutive l
constexpr int STR = 68;           // LDS row stride: 16B-aligned rows, <=2-way banks
constexpr float EPS_ = 1e-6f;
}

__device__ __forceinline__ float phi(float x) {
    // elu(x)+1 = x+1 (x>0) else exp(x)
    return x > 0.0f ? x + 1.0f : __expf(x);
}

// ---------------------------------------------------------------------------
// Kernel 1: per-chunk sums  S_chunk[d][m] = sum_j phi(K_j)[d] * V_j[m],
//           ksum_chunk[d]  = sum_j phi(K_j)[d]
// grid = NH*G blocks, 256 threads
// ---------------------------------------------------------------------------
__global__ __launch_bounds__(256) void k_chunksum(
    const float* __restrict__ keys, const float* __restrict__ values,
    float* __restrict__ wsS, float* __restrict__ wsK)
{
    __shared__ __align__(16) float Ks[C * STR];
    __shared__ __align__(16) float Vs[C * STR];
    const int bid = blockIdx.x;
    const int g = bid % G, nh = bid / G;
    const int n = nh / H_, h = nh % H_;
    const int t = threadIdx.x;
    const size_t base = ((size_t)(n * L_ + g * C) * H_ + h) * D_;

    // cooperative load: 64 rows x 16 float4 per array
#pragma unroll
    for (int r = 0; r < 4; ++r) {
        const int f = t + 256 * r;          // float4 index 0..1023
        const int row = f >> 4, c = (f & 15) * 4;
        const size_t ga = base + (size_t)row * LDH + c;
        float4 kv = *(const float4*)(keys + ga);
        float4 vv = *(const float4*)(values + ga);
        *(float4*)&Ks[row * STR + c] =
            make_float4(phi(kv.x), phi(kv.y), phi(kv.z), phi(kv.w));
        *(float4*)&Vs[row * STR + c] = vv;
    }
    __syncthreads();

    // 4x4 tile per thread: d0 rows of S, m0 cols; contract over j (rows)
    const int d0 = (t >> 4) * 4, m0 = (t & 15) * 4;
    float acc[4][4] = {};
#pragma unroll
    for (int j = 0; j < C; ++j) {
        const float4 k4 = *(const float4*)&Ks[j * STR + d0];
        const float4 v4 = *(const float4*)&Vs[j * STR + m0];
        const float ka[4] = {k4.x, k4.y, k4.z, k4.w};
        const float va[4] = {v4.x, v4.y, v4.z, v4.w};
#pragma unroll
        for (int a = 0; a < 4; ++a)
#pragma unroll
            for (int b = 0; b < 4; ++b)
                acc[a][b] += ka[a] * va[b];
    }
    float* Sc = wsS + (size_t)bid * (D_ * M_);
#pragma unroll
    for (int a = 0; a < 4; ++a)
        *(float4*)(Sc + (d0 + a) * M_ + m0) =
            make_float4(acc[a][0], acc[a][1], acc[a][2], acc[a][3]);

    if (t < D_) {
        float s = 0.f;
#pragma unroll
        for (int j = 0; j < C; ++j) s += Ks[j * STR + t];
        wsK[(size_t)bid * D_ + t] = s;
    }
}

// ---------------------------------------------------------------------------
// Kernel 2: exclusive prefix scan over chunks (elementwise over S and ksum)
// grid = NH*4 blocks, 256 threads; each thread scans one float4 lane
// ---------------------------------------------------------------------------
__global__ __launch_bounds__(256) void k_scan(
    float* __restrict__ wsS, float* __restrict__ wsK)
{
    const int bid = blockIdx.x;
    const int nh = bid >> 2, q = bid & 3;
    const int t = threadIdx.x;

    float4 run = make_float4(0.f, 0.f, 0.f, 0.f);
    float* base = wsS + (size_t)nh * G * (D_ * M_) + q * 1024 + (size_t)t * 4;
#pragma unroll
    for (int g = 0; g < G; ++g) {
        float4* p = (float4*)(base + (size_t)g * (D_ * M_));
        const float4 v = *p;
        *p = run;
        run.x += v.x; run.y += v.y; run.z += v.z; run.w += v.w;
    }

    if (q == 0 && t < D_ / 4) {
        float4 rk = make_float4(0.f, 0.f, 0.f, 0.f);
        float* kb = wsK + (size_t)nh * G * D_ + (size_t)t * 4;
#pragma unroll
        for (int g = 0; g < G; ++g) {
            float4* p = (float4*)(kb + (size_t)g * D_);
            const float4 v = *p;
            *p = rk;
            rk.x += v.x; rk.y += v.y; rk.z += v.z; rk.w += v.w;
        }
    }
}

// ---------------------------------------------------------------------------
// Kernel 3: per-chunk output
//   A = tril(phi(Q) phi(K)^T)            (64x64, in LDS, reusing K buffer)
//   Z_i = 1/(phi(Q_i).kprefix + rowsum(A)_i + eps)
//   out = (A @ V + phi(Q) @ Sprefix) * Z
// grid = NH*G blocks, 256 threads
// ---------------------------------------------------------------------------
__global__ __launch_bounds__(256) void k_out(
    const float* __restrict__ queries, const float* __restrict__ keys,
    const float* __restrict__ values, float* __restrict__ out,
    const float* __restrict__ wsS, const float* __restrict__ wsK)
{
    __shared__ __align__(16) float Qs[C * STR];
    __shared__ __align__(16) float KA[C * STR];   // phi(K), then reused for A
    __shared__ __align__(16) float Vs[C * STR];
    __shared__ float Zs[C];

    const int bid = blockIdx.x;
    const int g = bid % G, nh = bid / G;
    const int n = nh / H_, h = nh % H_;
    const int t = threadIdx.x;
    const size_t base = ((size_t)(n * L_ + g * C) * H_ + h) * D_;

#pragma unroll
    for (int r = 0; r < 4; ++r) {
        const int f = t + 256 * r;
        const int row = f >> 4, c = (f & 15) * 4;
        const size_t ga = base + (size_t)row * LDH + c;
        float4 qv = *(const float4*)(queries + ga);
        float4 kv = *(const float4*)(keys + ga);
        float4 vv = *(const float4*)(values + ga);
        *(float4*)&Qs[row * STR + c] =
            make_float4(phi(qv.x), phi(qv.y), phi(qv.z), phi(qv.w));
        *(float4*)&KA[row * STR + c] =
            make_float4(phi(kv.x), phi(kv.y), phi(kv.z), phi(kv.w));
        *(float4*)&Vs[row * STR + c] = vv;
    }
    __syncthreads();

    // ---- A = phi(Q) phi(K)^T, causal-masked -------------------------------
    // thread tile: i in {i0..i0+3}, j in {jt, jt+16, jt+32, jt+48}
    const int i0 = (t >> 4) * 4, jt = t & 15;
    float accA[4][4] = {};
#pragma unroll
    for (int d4 = 0; d4 < 16; ++d4) {
        float4 q4[4], k4[4];
#pragma unroll
        for (int a = 0; a < 4; ++a)
            q4[a] = *(const float4*)&Qs[(i0 + a) * STR + d4 * 4];
#pragma unroll
        for (int kk = 0; kk < 4; ++kk)
            k4[kk] = *(const float4*)&KA[(jt + 16 * kk) * STR + d4 * 4];
#pragma unroll
        for (int a = 0; a < 4; ++a)
#pragma unroll
            for (int kk = 0; kk < 4; ++kk)
                accA[a][kk] += q4[a].x * k4[kk].x + q4[a].y * k4[kk].y +
                               q4[a].z * k4[kk].z + q4[a].w * k4[kk].w;
    }
    __syncthreads();   // all reads of KA (=phi(K)) done

    // write masked A into the KA buffer (scalar writes, ~2-way banks)
#pragma unroll
    for (int a = 0; a < 4; ++a)
#pragma unroll
        for (int kk = 0; kk < 4; ++kk) {
            const int j = jt + 16 * kk;
            KA[(i0 + a) * STR + j] = (j <= i0 + a) ? accA[a][kk] : 0.f;
        }
    __syncthreads();

    // ---- Z ----------------------------------------------------------------
    const float* kpref = wsK + (size_t)(nh * G + g) * D_;
    if (t < C) {
        float rs = 0.f, zd = 0.f;
#pragma unroll
        for (int d4 = 0; d4 < 16; ++d4) {
            const float4 a4 = *(const float4*)&KA[t * STR + d4 * 4];
            rs += (a4.x + a4.y) + (a4.z + a4.w);
            const float4 q4 = *(const float4*)&Qs[t * STR + d4 * 4];
            const float4 kp4 = *(const float4*)(kpref + d4 * 4);
            zd += q4.x * kp4.x + q4.y * kp4.y + q4.z * kp4.z + q4.w * kp4.w;
        }
        Zs[t] = 1.0f / (zd + rs + EPS_);
    }
    __syncthreads();

    // ---- out = (A @ V + Q @ Sprefix) * Z ----------------------------------
    const float* Sp = wsS + (size_t)(nh * G + g) * (D_ * M_);
    const int m0 = (t & 15) * 4;
    float acc[4][4] = {};

#pragma unroll
    for (int j4 = 0; j4 < 16; ++j4) {
        float av[4][4], vv[4][4];
#pragma unroll
        for (int a = 0; a < 4; ++a) {
            const float4 x = *(const float4*)&KA[(i0 + a) * STR + j4 * 4];
            av[a][0] = x.x; av[a][1] = x.y; av[a][2] = x.z; av[a][3] = x.w;
        }
#pragma unroll
        for (int jj = 0; jj < 4; ++jj) {
            const float4 x = *(const float4*)&Vs[(j4 * 4 + jj) * STR + m0];
            vv[jj][0] = x.x; vv[jj][1] = x.y; vv[jj][2] = x.z; vv[jj][3] = x.w;
        }
#pragma unroll
        for (int a = 0; a < 4; ++a)
#pragma unroll
            for (int jj = 0; jj < 4; ++jj)
#pragma unroll
                for (int m = 0; m < 4; ++m)
                    acc[a][m] += av[a][jj] * vv[jj][m];
    }

#pragma unroll
    for (int d4 = 0; d4 < 16; ++d4) {
        float qv[4][4], sv[4][4];
#pragma unroll
        for (int a = 0; a < 4; ++a) {
            const float4 x = *(const float4*)&Qs[(i0 + a) * STR + d4 * 4];
            qv[a][0] = x.x; qv[a][1] = x.y; qv[a][2] = x.z; qv[a][3] = x.w;
        }
#pragma unroll
        for (int dd = 0; dd < 4; ++dd) {
            const float4 x = *(const float4*)(Sp + (d4 * 4 + dd) * M_ + m0);
            sv[dd][0] = x.x; sv[dd][1] = x.y; sv[dd][2] = x.z; sv[dd][3] = x.w;
        }
#pragma unroll
        for (int a = 0; a < 4; ++a)
#pragma unroll
            for (int dd = 0; dd < 4; ++dd)
#pragma unroll
                for (int m = 0; m < 4; ++m)
                    acc[a][m] += qv[a][dd] * sv[dd][m];
    }

#pragma unroll
    for (int a = 0; a < 4; ++a) {
        const float z = Zs[i0 + a];
        const size_t oa = ((size_t)(n * L_ + g * C + i0 + a) * H_ + h) * M_ + m0;
        *(float4*)(out + oa) =
            make_float4(acc[a][0] * z, acc[a][1] * z, acc[a][2] * z, acc[a][3] * z);
    }
}

extern "C" void kernel_launch(void* const* d_in, const int* in_sizes, int n_in,
                              void* d_out, int out_size, void* d_ws, size_t ws_size,
                              hipStream_t stream) {
    const float* q = (const float*)d_in[0];
    const float* k = (const float*)d_in[1];
    const float* v = (const float*)d_in[2];
    float* out = (float*)d_out;
    float* wsS = (float*)d_ws;                              // NH*G*D*M floats (8 MB)
    float* wsK = wsS + (size_t)NH * G * D_ * M_;            // NH*G*D floats (128 KB)

    k_chunksum<<<dim3(NH * G), dim3(256), 0, stream>>>(k, v, wsS, wsK);
    k_scan<<<dim3(NH * 4), dim3(256), 0, stream>>>(wsS, wsK);
    k_out<<<dim3(NH * G), dim3(256), 0, stream>>>(q, k, v, out, wsS, wsK);
}

// Round 2
// 99.425 us; speedup vs baseline: 1.1256x; 1.1256x over previous
//
#include <hip/hip_runtime.h>

// Causal linear attention (elu+1 feature map), chunked-scan formulation.
// Shapes fixed by the reference: N=2, L=2048, H=8, D=64, M=64, fp32.
//
// R2: spill-free k_out — no register staging arrays, direct float4 consumption,
// __launch_bounds__(256,4) to cap VGPR<=128 (3 blocks/CU, LDS-limited).

namespace {
constexpr int N_ = 2, L_ = 2048, H_ = 8, D_ = 64, M_ = 64;
constexpr int C  = 64;            // chunk length
constexpr int G  = L_ / C;        // 32 chunks per sequence
constexpr int NH = N_ * H_;       // 16 independent (n,h) sequences
constexpr int LDH = H_ * D_;      // stride (floats) between consecutive l
constexpr int STR = 68;           // LDS row stride: 16B-aligned rows, <=2-way banks
constexpr float EPS_ = 1e-6f;
}

__device__ __forceinline__ float phi(float x) {
    return x > 0.0f ? x + 1.0f : __expf(x);
}

// ---------------------------------------------------------------------------
// Kernel 1: per-chunk sums  S_chunk[d][m] = sum_j phi(K_j)[d] * V_j[m],
//           ksum_chunk[d]  = sum_j phi(K_j)[d]
// ---------------------------------------------------------------------------
__global__ __launch_bounds__(256, 4) void k_chunksum(
    const float* __restrict__ keys, const float* __restrict__ values,
    float* __restrict__ wsS, float* __restrict__ wsK)
{
    __shared__ __align__(16) float Ks[C * STR];
    __shared__ __align__(16) float Vs[C * STR];
    const int bid = blockIdx.x;
    const int g = bid % G, nh = bid / G;
    const int n = nh / H_, h = nh % H_;
    const int t = threadIdx.x;
    const size_t base = ((size_t)(n * L_ + g * C) * H_ + h) * D_;

#pragma unroll
    for (int r = 0; r < 4; ++r) {
        const int f = t + 256 * r;
        const int row = f >> 4, c = (f & 15) * 4;
        const size_t ga = base + (size_t)row * LDH + c;
        float4 kv = *(const float4*)(keys + ga);
        float4 vv = *(const float4*)(values + ga);
        *(float4*)&Ks[row * STR + c] =
            make_float4(phi(kv.x), phi(kv.y), phi(kv.z), phi(kv.w));
        *(float4*)&Vs[row * STR + c] = vv;
    }
    __syncthreads();

    const int d0 = (t >> 4) * 4, m0 = (t & 15) * 4;
    float acc[4][4] = {};
#pragma unroll 8
    for (int j = 0; j < C; ++j) {
        const float4 k4 = *(const float4*)&Ks[j * STR + d0];
        const float4 v4 = *(const float4*)&Vs[j * STR + m0];
        acc[0][0] = fmaf(k4.x, v4.x, acc[0][0]);
        acc[0][1] = fmaf(k4.x, v4.y, acc[0][1]);
        acc[0][2] = fmaf(k4.x, v4.z, acc[0][2]);
        acc[0][3] = fmaf(k4.x, v4.w, acc[0][3]);
        acc[1][0] = fmaf(k4.y, v4.x, acc[1][0]);
        acc[1][1] = fmaf(k4.y, v4.y, acc[1][1]);
        acc[1][2] = fmaf(k4.y, v4.z, acc[1][2]);
        acc[1][3] = fmaf(k4.y, v4.w, acc[1][3]);
        acc[2][0] = fmaf(k4.z, v4.x, acc[2][0]);
        acc[2][1] = fmaf(k4.z, v4.y, acc[2][1]);
        acc[2][2] = fmaf(k4.z, v4.z, acc[2][2]);
        acc[2][3] = fmaf(k4.z, v4.w, acc[2][3]);
        acc[3][0] = fmaf(k4.w, v4.x, acc[3][0]);
        acc[3][1] = fmaf(k4.w, v4.y, acc[3][1]);
        acc[3][2] = fmaf(k4.w, v4.z, acc[3][2]);
        acc[3][3] = fmaf(k4.w, v4.w, acc[3][3]);
    }
    float* Sc = wsS + (size_t)bid * (D_ * M_);
#pragma unroll
    for (int a = 0; a < 4; ++a)
        *(float4*)(Sc + (d0 + a) * M_ + m0) =
            make_float4(acc[a][0], acc[a][1], acc[a][2], acc[a][3]);

    if (t < D_) {
        float s = 0.f;
#pragma unroll
        for (int j = 0; j < C; ++j) s += Ks[j * STR + t];
        wsK[(size_t)bid * D_ + t] = s;
    }
}

// ---------------------------------------------------------------------------
// Kernel 2: exclusive prefix scan over chunks
// ---------------------------------------------------------------------------
__global__ __launch_bounds__(256) void k_scan(
    float* __restrict__ wsS, float* __restrict__ wsK)
{
    const int bid = blockIdx.x;
    const int nh = bid >> 2, q = bid & 3;
    const int t = threadIdx.x;

    float4 run = make_float4(0.f, 0.f, 0.f, 0.f);
    float* base = wsS + (size_t)nh * G * (D_ * M_) + q * 1024 + (size_t)t * 4;
#pragma unroll
    for (int g = 0; g < G; ++g) {
        float4* p = (float4*)(base + (size_t)g * (D_ * M_));
        const float4 v = *p;
        *p = run;
        run.x += v.x; run.y += v.y; run.z += v.z; run.w += v.w;
    }

    if (q == 0 && t < D_ / 4) {
        float4 rk = make_float4(0.f, 0.f, 0.f, 0.f);
        float* kb = wsK + (size_t)nh * G * D_ + (size_t)t * 4;
#pragma unroll
        for (int g = 0; g < G; ++g) {
            float4* p = (float4*)(kb + (size_t)g * D_);
            const float4 v = *p;
            *p = rk;
            rk.x += v.x; rk.y += v.y; rk.z += v.z; rk.w += v.w;
        }
    }
}

// ---------------------------------------------------------------------------
// Kernel 3: per-chunk output
//   A = tril(phi(Q) phi(K)^T); Z = 1/(phi(Q).kprefix + rowsum(A) + eps)
//   out = (A @ V + phi(Q) @ Sprefix) * Z
// ---------------------------------------------------------------------------
__global__ __launch_bounds__(256, 4) void k_out(
    const float* __restrict__ queries, const float* __restrict__ keys,
    const float* __restrict__ values, float* __restrict__ out,
    const float* __restrict__ wsS, const float* __restrict__ wsK)
{
    __shared__ __align__(16) float Qs[C * STR];
    __shared__ __align__(16) float KA[C * STR];   // phi(K), then reused for A
    __shared__ __align__(16) float Vs[C * STR];
    __shared__ float Zs[C];

    const int bid = blockIdx.x;
    const int g = bid % G, nh = bid / G;
    const int n = nh / H_, h = nh % H_;
    const int t = threadIdx.x;
    const size_t base = ((size_t)(n * L_ + g * C) * H_ + h) * D_;

#pragma unroll
    for (int r = 0; r < 4; ++r) {
        const int f = t + 256 * r;
        const int row = f >> 4, c = (f & 15) * 4;
        const size_t ga = base + (size_t)row * LDH + c;
        float4 qv = *(const float4*)(queries + ga);
        float4 kv = *(const float4*)(keys + ga);
        float4 vv = *(const float4*)(values + ga);
        *(float4*)&Qs[row * STR + c] =
            make_float4(phi(qv.x), phi(qv.y), phi(qv.z), phi(qv.w));
        *(float4*)&KA[row * STR + c] =
            make_float4(phi(kv.x), phi(kv.y), phi(kv.z), phi(kv.w));
        *(float4*)&Vs[row * STR + c] = vv;
    }
    __syncthreads();

    const int i0 = (t >> 4) * 4, jt = t & 15, m0 = (t & 15) * 4;

    // ---- A = phi(Q) phi(K)^T ---------------------------------------------
    float accA[4][4] = {};
#pragma unroll 4
    for (int d4 = 0; d4 < 16; ++d4) {
        const int dc = d4 * 4;
        const float4 k0 = *(const float4*)&KA[(jt     ) * STR + dc];
        const float4 k1 = *(const float4*)&KA[(jt + 16) * STR + dc];
        const float4 k2 = *(const float4*)&KA[(jt + 32) * STR + dc];
        const float4 k3 = *(const float4*)&KA[(jt + 48) * STR + dc];
#pragma unroll
        for (int a = 0; a < 4; ++a) {
            const float4 q4 = *(const float4*)&Qs[(i0 + a) * STR + dc];
            accA[a][0] += q4.x * k0.x + q4.y * k0.y + q4.z * k0.z + q4.w * k0.w;
            accA[a][1] += q4.x * k1.x + q4.y * k1.y + q4.z * k1.z + q4.w * k1.w;
            accA[a][2] += q4.x * k2.x + q4.y * k2.y + q4.z * k2.z + q4.w * k2.w;
            accA[a][3] += q4.x * k3.x + q4.y * k3.y + q4.z * k3.z + q4.w * k3.w;
        }
    }
    __syncthreads();   // all reads of KA (=phi(K)) done

#pragma unroll
    for (int a = 0; a < 4; ++a) {
        const int i = i0 + a;
        KA[i * STR + jt]      = (jt      <= i) ? accA[a][0] : 0.f;
        KA[i * STR + jt + 16] = (jt + 16 <= i) ? accA[a][1] : 0.f;
        KA[i * STR + jt + 32] = (jt + 32 <= i) ? accA[a][2] : 0.f;
        KA[i * STR + jt + 48] = (jt + 48 <= i) ? accA[a][3] : 0.f;
    }
    __syncthreads();

    // ---- Z ----------------------------------------------------------------
    const float* kpref = wsK + (size_t)(nh * G + g) * D_;
    if (t < C) {
        float rs = 0.f, zd = 0.f;
#pragma unroll
        for (int d4 = 0; d4 < 16; ++d4) {
            const float4 a4 = *(const float4*)&KA[t * STR + d4 * 4];
            rs += (a4.x + a4.y) + (a4.z + a4.w);
            const float4 q4 = *(const float4*)&Qs[t * STR + d4 * 4];
            const float4 kp4 = *(const float4*)(kpref + d4 * 4);
            zd += q4.x * kp4.x + q4.y * kp4.y + q4.z * kp4.z + q4.w * kp4.w;
        }
        Zs[t] = 1.0f / (zd + rs + EPS_);
    }
    __syncthreads();

    // ---- out = (A @ V + Q @ Sprefix) * Z ----------------------------------
    const float* Sp = wsS + (size_t)(nh * G + g) * (D_ * M_);
    float acc[4][4] = {};

    // A @ V : A rows read as float4 along j (broadcast within i0-group)
#pragma unroll 4
    for (int j4 = 0; j4 < 16; ++j4) {
        const int jc = j4 * 4;
        const float4 a0 = *(const float4*)&KA[(i0 + 0) * STR + jc];
        const float4 a1 = *(const float4*)&KA[(i0 + 1) * STR + jc];
        const float4 a2 = *(const float4*)&KA[(i0 + 2) * STR + jc];
        const float4 a3 = *(const float4*)&KA[(i0 + 3) * STR + jc];
#pragma unroll
        for (int jj = 0; jj < 4; ++jj) {
            const float4 v4 = *(const float4*)&Vs[(jc + jj) * STR + m0];
            const float w0 = jj == 0 ? a0.x : jj == 1 ? a0.y : jj == 2 ? a0.z : a0.w;
            const float w1 = jj == 0 ? a1.x : jj == 1 ? a1.y : jj == 2 ? a1.z : a1.w;
            const float w2 = jj == 0 ? a2.x : jj == 1 ? a2.y : jj == 2 ? a2.z : a2.w;
            const float w3 = jj == 0 ? a3.x : jj == 1 ? a3.y : jj == 2 ? a3.z : a3.w;
            acc[0][0] = fmaf(w0, v4.x, acc[0][0]);
            acc[0][1] = fmaf(w0, v4.y, acc[0][1]);
            acc[0][2] = fmaf(w0, v4.z, acc[0][2]);
            acc[0][3] = fmaf(w0, v4.w, acc[0][3]);
            acc[1][0] = fmaf(w1, v4.x, acc[1][0]);
            acc[1][1] = fmaf(w1, v4.y, acc[1][1]);
            acc[1][2] = fmaf(w1, v4.z, acc[1][2]);
            acc[1][3] = fmaf(w1, v4.w, acc[1][3]);
            acc[2][0] = fmaf(w2, v4.x, acc[2][0]);
            acc[2][1] = fmaf(w2, v4.y, acc[2][1]);
            acc[2][2] = fmaf(w2, v4.z, acc[2][2]);
            acc[2][3] = fmaf(w2, v4.w, acc[2][3]);
            acc[3][0] = fmaf(w3, v4.x, acc[3][0]);
            acc[3][1] = fmaf(w3, v4.y, acc[3][1]);
            acc[3][2] = fmaf(w3, v4.z, acc[3][2]);
            acc[3][3] = fmaf(w3, v4.w, acc[3][3]);
        }
    }

    // Q @ Sprefix : S rows from global (L1/L2-cached, coalesced per wave)
#pragma unroll 4
    for (int d4 = 0; d4 < 16; ++d4) {
        const int dc = d4 * 4;
        const float4 q0 = *(const float4*)&Qs[(i0 + 0) * STR + dc];
        const float4 q1 = *(const float4*)&Qs[(i0 + 1) * STR + dc];
        const float4 q2 = *(const float4*)&Qs[(i0 + 2) * STR + dc];
        const float4 q3 = *(const float4*)&Qs[(i0 + 3) * STR + dc];
#pragma unroll
        for (int dd = 0; dd < 4; ++dd) {
            const float4 s4 = *(const float4*)(Sp + (dc + dd) * M_ + m0);
            const float w0 = dd == 0 ? q0.x : dd == 1 ? q0.y : dd == 2 ? q0.z : q0.w;
            const float w1 = dd == 0 ? q1.x : dd == 1 ? q1.y : dd == 2 ? q1.z : q1.w;
            const float w2 = dd == 0 ? q2.x : dd == 1 ? q2.y : dd == 2 ? q2.z : q2.w;
            const float w3 = dd == 0 ? q3.x : dd == 1 ? q3.y : dd == 2 ? q3.z : q3.w;
            acc[0][0] = fmaf(w0, s4.x, acc[0][0]);
            acc[0][1] = fmaf(w0, s4.y, acc[0][1]);
            acc[0][2] = fmaf(w0, s4.z, acc[0][2]);
            acc[0][3] = fmaf(w0, s4.w, acc[0][3]);
            acc[1][0] = fmaf(w1, s4.x, acc[1][0]);
            acc[1][1] = fmaf(w1, s4.y, acc[1][1]);
            acc[1][2] = fmaf(w1, s4.z, acc[1][2]);
            acc[1][3] = fmaf(w1, s4.w, acc[1][3]);
            acc[2][0] = fmaf(w2, s4.x, acc[2][0]);
            acc[2][1] = fmaf(w2, s4.y, acc[2][1]);
            acc[2][2] = fmaf(w2, s4.z, acc[2][2]);
            acc[2][3] = fmaf(w2, s4.w, acc[2][3]);
            acc[3][0] = fmaf(w3, s4.x, acc[3][0]);
            acc[3][1] = fmaf(w3, s4.y, acc[3][1]);
            acc[3][2] = fmaf(w3, s4.z, acc[3][2]);
            acc[3][3] = fmaf(w3, s4.w, acc[3][3]);
        }
    }

#pragma unroll
    for (int a = 0; a < 4; ++a) {
        const float z = Zs[i0 + a];
        const size_t oa = ((size_t)(n * L_ + g * C + i0 + a) * H_ + h) * M_ + m0;
        *(float4*)(out + oa) =
            make_float4(acc[a][0] * z, acc[a][1] * z, acc[a][2] * z, acc[a][3] * z);
    }
}

extern "C" void kernel_launch(void* const* d_in, const int* in_sizes, int n_in,
                              void* d_out, int out_size, void* d_ws, size_t ws_size,
                              hipStream_t stream) {
    const float* q = (const float*)d_in[0];
    const float* k = (const float*)d_in[1];
    const float* v = (const float*)d_in[2];
    float* out = (float*)d_out;
    float* wsS = (float*)d_ws;                              // NH*G*D*M floats (8 MB)
    float* wsK = wsS + (size_t)NH * G * D_ * M_;            // NH*G*D floats (128 KB)

    k_chunksum<<<dim3(NH * G), dim3(256), 0, stream>>>(k, v, wsS, wsK);
    k_scan<<<dim3(NH * 4), dim3(256), 0, stream>>>(wsS, wsK);
    k_out<<<dim3(NH * G), dim3(256), 0, stream>>>(q, k, v, out, wsS, wsK);
}